// Round 21
// baseline (111.505 us; speedup 1.0000x reference)
//
#include <hip/hip_runtime.h>
#include <cstdint>

typedef __attribute__((ext_vector_type(4))) short s16x4;
typedef __attribute__((ext_vector_type(8))) short s16x8;
typedef __attribute__((ext_vector_type(4))) float f32x4;
typedef __attribute__((ext_vector_type(16))) float f32x16;

#define L2E 1.44269504088896340736f

__device__ __forceinline__ short f2bf(float f) {
  union { float f; unsigned u; } v; v.f = f;
  unsigned r = (v.u + 0x7fffu + ((v.u >> 16) & 1u)) >> 16;
  return (short)r;
}

// cross-half (lane ^ 32) exchange via permlane32_swap — pure VALU, no LDS.
__device__ __forceinline__ float xhalf_f(float x) {
  union { float f; unsigned u; } a; a.f = x;
  auto r = __builtin_amdgcn_permlane32_swap(a.u, a.u, false, false);
  union { unsigned u; float f; } b;
  b.u = (threadIdx.x & 32) ? r[0] : r[1];
  return b.f;
}

typedef const __attribute__((address_space(1))) unsigned int* gas_p;
typedef __attribute__((address_space(3))) unsigned int* las_p;
__device__ __forceinline__ void stage16(const void* g, void* l) {
  __builtin_amdgcn_global_load_lds((gas_p)(uintptr_t)g,
                                   (las_p)(unsigned int)(uintptr_t)l, 16, 0, 0);
}

// ---- fused pre-pass: z<4 -> transpose W_z (1024x1024 fp32 -> bf16 [N][K]);
//      z>=4 -> cvt slab of x (fp32 -> bf16). One dispatch. ----
__global__ __launch_bounds__(256) void prepass(const float* __restrict__ W0,
                                               const float* __restrict__ W1,
                                               const float* __restrict__ W2,
                                               const float* __restrict__ W3,
                                               short* __restrict__ wdst,
                                               const float* __restrict__ x,
                                               short* __restrict__ xb) {
  const int z = blockIdx.z;
  const int t = threadIdx.x;
  if (z >= 4) {
    int i = ((z - 4) * 256 + blockIdx.y * 16 + blockIdx.x) * 256 + t;
    const f32x4* p = (const f32x4*)x + (size_t)i * 2;
    f32x4 a = p[0], b = p[1];
    s16x8 o;
    o[0] = f2bf(a[0]); o[1] = f2bf(a[1]); o[2] = f2bf(a[2]); o[3] = f2bf(a[3]);
    o[4] = f2bf(b[0]); o[5] = f2bf(b[1]); o[6] = f2bf(b[2]); o[7] = f2bf(b[3]);
    *((s16x8*)xb + i) = o;
    return;
  }
  __shared__ float tile[64][65];
  const float* in = (z == 0) ? W0 : (z == 1) ? W1 : (z == 2) ? W2 : W3;
  short* out = wdst + (size_t)z * 1048576;
  const int bi = blockIdx.y, bj = blockIdx.x;
  const int c = t & 63, r0 = t >> 6;
#pragma unroll
  for (int i = 0; i < 16; i++) {
    int r = r0 + i * 4;
    tile[r][c] = in[(size_t)(bi * 64 + r) * 1024 + bj * 64 + c];
  }
  __syncthreads();
#pragma unroll
  for (int i = 0; i < 16; i++) {
    int r = r0 + i * 4;
    out[(size_t)(bj * 64 + r) * 1024 + bi * 64 + c] = f2bf(tile[c][r]);
  }
}

// ======== QKV GEMM: 8-phase 256x192 schedule (full CU coverage, r20) ========
__global__ __launch_bounds__(512) void gemm_qkv8(
    const short* __restrict__ A, const short* __restrict__ B,
    const float* __restrict__ b0, const float* __restrict__ b1,
    const float* __restrict__ b2, short* __restrict__ o0,
    short* __restrict__ o1, short* __restrict__ o2) {
  constexpr int K = 1024, NKT = 16;
  constexpr int BUFS = 28672;  // shorts per parity buffer (A 16384 + B 12288)
  __shared__ short L[2 * BUFS];  // 112 KB
  const int tid = threadIdx.x;
  const int lane = tid & 63, wave = tid >> 6;
  const int wr = wave >> 2, wc = wave & 3;
  const int l15 = lane & 15, l4 = lane >> 4;
  const int id = blockIdx.x;
  const int wgid = (id & 7) * 32 + (id >> 3);
  const int m0 = (wgid & 15) * 256;
  const int n0 = (wgid >> 4) * 192;
  const short* Asrc = A + (size_t)m0 * K;
  const short* Bsrc = B + (size_t)n0 * K;

  f32x4 acc[8][3];
#pragma unroll
  for (int i = 0; i < 8; i++)
#pragma unroll
    for (int j = 0; j < 3; j++) acc[i][j] = (f32x4){0.f, 0.f, 0.f, 0.f};

  int sALo[2], gALo[2], sBLo[2], gBLo[2];
#pragma unroll
  for (int j = 0; j < 2; j++) {
    const int flat = j * 512 + tid;
    const int r = flat >> 3, ch = flat & 7;
    const int sw8 = ((ch ^ (r & 7)) << 3);
    sALo[j] = (r >> 6) * 8192 + (r & 63) * 64 + (ch << 3);
    gALo[j] = ((r >> 6) * 128 + (r & 63)) * K + sw8;
    sBLo[j] = 16384 + (flat << 3);
    gBLo[j] = r * K + sw8;
  }
  const int rBH = 128 + (tid >> 3), chBH = tid & 7;
  const int sBHi = 16384 + rBH * 64 + (chBH << 3);
  const int gBHi = rBH * K + ((chBH ^ (rBH & 7)) << 3);

  int aoff[2], boff[2];
#pragma unroll
  for (int kf = 0; kf < 2; kf++) {
    const int x = (((kf << 2) + l4) ^ (l15 & 7)) << 3;
    aoff[kf] = wr * 8192 + l15 * 64 + x;
    boff[kf] = 16384 + (wc * 48 + l15) * 64 + x;
  }

#define ST_ALO(BB, T)                                                          \
  { _Pragma("unroll") for (int j_ = 0; j_ < 2; j_++)                           \
        stage16(Asrc + gALo[j_] + (T)*64, L + (BB) + sALo[j_]); }
#define ST_AHI(BB, T)                                                          \
  { _Pragma("unroll") for (int j_ = 0; j_ < 2; j_++)                           \
        stage16(Asrc + gALo[j_] + 64 * K + (T)*64, L + (BB) + sALo[j_] + 4096); }
#define ST_BLO(BB, T)                                                          \
  { _Pragma("unroll") for (int j_ = 0; j_ < 2; j_++)                           \
        stage16(Bsrc + gBLo[j_] + (T)*64, L + (BB) + sBLo[j_]); }
#define ST_BHI(BB, T)                                                          \
  stage16(Bsrc + gBHi + (T)*64, L + (BB) + sBHi);

#define RD_A(MI0)                                                              \
  { _Pragma("unroll") for (int q_ = 0; q_ < 2; q_++)                           \
        _Pragma("unroll") for (int kf_ = 0; kf_ < 2; kf_++)                    \
            af[q_][kf_] = *(const s16x8*)(bc + aoff[kf_] + ((MI0) + q_) * 1024); }

#define BAR_MFMA(MI0)                                                          \
  __builtin_amdgcn_s_barrier();                                                \
  asm volatile("s_waitcnt lgkmcnt(0)" ::: "memory");                           \
  __builtin_amdgcn_sched_barrier(0);                                           \
  __builtin_amdgcn_s_setprio(1);                                               \
  _Pragma("unroll") for (int q_ = 0; q_ < 2; q_++)                             \
      _Pragma("unroll") for (int ni_ = 0; ni_ < 3; ni_++)                      \
          _Pragma("unroll") for (int kf_ = 0; kf_ < 2; kf_++)                  \
              acc[(MI0) + q_][ni_] = __builtin_amdgcn_mfma_f32_16x16x32_bf16(  \
                  af[q_][kf_], bf[ni_][kf_], acc[(MI0) + q_][ni_], 0, 0, 0);   \
  __builtin_amdgcn_s_setprio(0);                                               \
  __builtin_amdgcn_s_barrier();

  ST_ALO(0, 0) ST_AHI(0, 0) ST_BLO(0, 0) ST_BHI(0, 0)
  ST_BLO(BUFS, 1) ST_BHI(BUFS, 1) ST_ALO(BUFS, 1)
  asm volatile("s_waitcnt vmcnt(5)" ::: "memory");
  __builtin_amdgcn_s_barrier();

  int bufc = 0;
  for (int t = 0; t < NKT; ++t) {
    const int bufn = bufc ^ BUFS;
    const short* bc = L + bufc;
    s16x8 bf[3][2], af[2][2];
#pragma unroll
    for (int ni_ = 0; ni_ < 3; ni_++)
#pragma unroll
      for (int kf_ = 0; kf_ < 2; kf_++)
        bf[ni_][kf_] = *(const s16x8*)(bc + boff[kf_] + ni_ * 1024);
    RD_A(0)
    if (t + 1 < NKT) ST_AHI(bufn, t + 1)
    BAR_MFMA(0)
    RD_A(2)
    if (t + 2 < NKT) ST_BLO(bufc, t + 2)
    BAR_MFMA(2)
    RD_A(4)
    if (t + 2 < NKT) ST_BHI(bufc, t + 2)
    BAR_MFMA(4)
    RD_A(6)
    if (t + 2 < NKT) {
      ST_ALO(bufc, t + 2)
      asm volatile("s_waitcnt vmcnt(5)" ::: "memory");
    } else {
      asm volatile("s_waitcnt vmcnt(0)" ::: "memory");
    }
    BAR_MFMA(6)
    bufc = bufn;
  }
#undef ST_ALO
#undef ST_AHI
#undef ST_BLO
#undef ST_BHI
#undef RD_A
#undef BAR_MFMA

#pragma unroll
  for (int ni = 0; ni < 3; ni++) {
    const int col = n0 + wc * 48 + ni * 16 + l15;
    const float* bp; short* dst; int c1; int isV = 0; float scl = 1.0f;
    if (col < 1024) { bp = b0; dst = o0; c1 = col; scl = 0.125f * L2E; }
    else if (col < 2048) { bp = b1; dst = o1; c1 = col - 1024; }
    else { bp = b2; dst = o2; c1 = col - 2048; isV = 1; }
    const float bias = bp[c1];
    const int h = c1 >> 6, d = c1 & 63;
    if (isV) {
#pragma unroll
      for (int mi = 0; mi < 8; mi++) {
        int t0 = m0 + wr * 128 + mi * 16 + l4 * 4;
        int bb = t0 >> 11, tt = t0 & 2047;
        s16x4 ov;
#pragma unroll
        for (int rr = 0; rr < 4; rr++) ov[rr] = f2bf(acc[mi][ni][rr] + bias);
        *(s16x4*)(dst + (size_t)((bb * 16 + h) * 64 + d) * 2048 + tt) = ov;
      }
    } else {
#pragma unroll
      for (int mi = 0; mi < 8; mi++)
#pragma unroll
        for (int rr = 0; rr < 4; rr++) {
          int row = m0 + wr * 128 + mi * 16 + l4 * 4 + rr;
          int bb = row >> 11, tt = row & 2047;
          float v = (acc[mi][ni][rr] + bias) * scl;
          dst[(size_t)((bb * 16 + h) * 2048 + tt) * 64 + d] = f2bf(v);
        }
    }
  }
}

// ---------------- proj GEMM: 2-phase pipeline ----------------
template <int EPI, int BM>
__global__ __launch_bounds__(BM * 2) void gemm_bt(
    const short* __restrict__ A, const short* __restrict__ B, int N, int K,
    const float* __restrict__ b0, float* __restrict__ ofp) {
  constexpr int T = BM * 2;
  constexpr int AR = 2;
  constexpr int BR = 512 / T;
  constexpr int BUFB = (BM + 128) * 32;
  __shared__ short L[2 * BUFB];
  const int tid = threadIdx.x;
  const int lane = tid & 63;
  const int wave = tid >> 6;
  const int wr = wave >> 1, wc = wave & 1;
  const int l15 = lane & 15, l4 = lane >> 4;
  const int id = blockIdx.x + gridDim.x * blockIdx.y;
  const int cpx = gridDim.x >> 3;
  const int xcd = id & 7, sub = id >> 3;
  const int m0 = (sub / cpx) * BM;
  const int n0 = (xcd * cpx + sub % cpx) * 128;
  f32x4 acc[4][4];
#pragma unroll
  for (int i = 0; i < 4; i++)
#pragma unroll
    for (int j = 0; j < 4; j++) acc[i][j] = (f32x4){0.f, 0.f, 0.f, 0.f};

  const int lq = tid & 3, lr = tid >> 2;
  int soffA[AR], goffA[AR];
#pragma unroll
  for (int i = 0; i < AR; i++) {
    const int r = i * (T / 4) + lr;
    soffA[i] = r * 32 + lq * 8;
    goffA[i] = r * K + lq * 8;
  }
  int soffB[BR], goffB[BR];
#pragma unroll
  for (int j = 0; j < BR; j++) {
    const int r = j * (T / 4) + lr;
    soffB[j] = BM * 32 + r * 32 + lq * 8;
    goffB[j] = r * K + lq * 8;
  }

  const short* Asrc = A + (size_t)m0 * K;
  const short* Bsrc = B + (size_t)n0 * K;
  short* bufC = L;
  short* bufN = L + BUFB;

#define GSTAGE(BUF)                                                            \
  {                                                                            \
    _Pragma("unroll") for (int i_ = 0; i_ < AR; i_++)                          \
        stage16(Asrc + goffA[i_], (BUF) + soffA[i_]);                          \
    _Pragma("unroll") for (int j_ = 0; j_ < BR; j_++)                          \
        stage16(Bsrc + goffB[j_], (BUF) + soffB[j_]);                          \
    Asrc += 32; Bsrc += 32;                                                    \
  }

  GSTAGE(bufC)
  const int NK = K >> 5;
  for (int kt = 0; kt < NK; kt++) {
    __syncthreads();
    if (kt + 1 < NK) GSTAGE(bufN)
    s16x8 af[4], bfr[4];
#pragma unroll
    for (int i = 0; i < 4; i++) {
      af[i] = *(const s16x8*)(bufC + (wr * 64 + i * 16 + l15) * 32 + l4 * 8);
      bfr[i] = *(const s16x8*)(bufC + BM * 32 + (wc * 64 + i * 16 + l15) * 32 + l4 * 8);
    }
#pragma unroll
    for (int mi = 0; mi < 4; mi++)
#pragma unroll
      for (int ni = 0; ni < 4; ni++)
        acc[mi][ni] = __builtin_amdgcn_mfma_f32_16x16x32_bf16(af[mi], bfr[ni],
                                                              acc[mi][ni], 0, 0, 0);
    short* t_ = bufC; bufC = bufN; bufN = t_;
  }
#undef GSTAGE

#pragma unroll
  for (int ni = 0; ni < 4; ni++) {
    const int col = n0 + wc * 64 + ni * 16 + l15;
    const float bias = b0[col];
#pragma unroll
    for (int mi = 0; mi < 4; mi++)
#pragma unroll
      for (int r = 0; r < 4; r++) {
        int row = m0 + wr * 64 + mi * 16 + l4 * 4 + r;
        ofp[(size_t)row * N + col] = acc[mi][ni][r] + bias;
      }
  }
}

// ---- causal flash attention v11: BARRIER-FREE wave-private pipelines ----
// Block = 128 thr (2 waves); each wave owns 32 q-rows AND a private 40 KB
// LDS region (K dbuf 2x8KB + V tribuf 3x8KB). Each wave stages its own K/V
// tiles (16 global_load_lds/tile) and orders them with its own per-wave
// s_waitcnt vmcnt(0) — NO s_barrier anywhere. Alias safety: STAGE(t+1)
// writes K[(t+1)&1] / V[(t+1)%3], last read at iter t-1 (a full iteration
// earlier). Schedule per iter: vmcnt(0) [tile t landed] -> issue stage(t+1)
// -> QK(t) -> softmax+PV(t-1). LDS 80 KB/block -> 2 blocks/CU (160 KB exact).
// CU-balanced qt map and no-max softmax as in v8 (Q pre-scaled 0.125*L2E).
__global__ __launch_bounds__(128) void attn_v11(const short* __restrict__ Q,
                                                const short* __restrict__ K,
                                                const short* __restrict__ Vt,
                                                short* __restrict__ Y) {
  __shared__ short LW[2][20480];  // per-wave: K[2][4096] + V[3][4096] shorts
  const int bh = blockIdx.x;
  const int y = blockIdx.y;
  const int g = y >> 3, r_ = y & 7;
  const int qbase = (g << 3) | ((g & 1) ? (7 - r_) : r_);
  const int qt = (qbase + ((bh & 3) << 3)) & 31;
  const int tid = threadIdx.x, lane = tid & 63, wave = tid >> 6;
  const int q31 = lane & 31, hi = lane >> 5;
  const short* Qp = Q + (size_t)bh * 2048 * 64;
  const short* Kp = K + (size_t)bh * 2048 * 64;
  const short* Vp = Vt + (size_t)bh * 64 * 2048;
  const int qrow = qt * 64 + wave * 32 + q31;
  const int nt = qt + 1;
  const int cx = q31 & 7;

  s16x8 qf[4];  // Q pre-scaled by 0.125*L2E
#pragma unroll
  for (int s = 0; s < 4; s++)
    qf[s] = *(const s16x8*)(Qp + (size_t)qrow * 64 + s * 16 + hi * 8);

  f32x16 accA, accB, Z;
#pragma unroll
  for (int i = 0; i < 16; i++) { accA[i] = 0.f; accB[i] = 0.f; Z[i] = 0.f; }
  float l = 0.f;

  // per-wave staging: 8 rounds x 64 lanes x 16B = 8 KB per tile per matrix
  const int srow = lane >> 3, sch = lane & 7;
  int sdst[8], koff[8], voff[8];
#pragma unroll
  for (int j = 0; j < 8; j++) {
    const int r = j * 8 + srow;
    const int sc = sch ^ (r & 7);
    sdst[j] = r * 64 + sch * 8;
    koff[j] = r * 64 + sc * 8;
    voff[j] = r * 2048 + sc * 8;
  }
  const short* kst = Kp;
  const short* vst = Vp;
  int rd0[4];
#pragma unroll
  for (int s = 0; s < 4; s++) rd0[s] = q31 * 64 + (((2 * s + hi) ^ cx) << 3);

  short* base = &LW[wave][0];
  short* kA = base;          short* kB = base + 4096;
  short* vC = base + 8192;   short* vN = base + 12288;  short* vP = base + 16384;

  // prologue: tile 0 -> kA, vC
#pragma unroll
  for (int j = 0; j < 8; j++) {
    stage16(kst + koff[j], kA + sdst[j]);
    stage16(vst + voff[j], vC + sdst[j]);
  }
  kst += 4096; vst += 64;

#define SYNC                                                                   \
  asm volatile("s_waitcnt vmcnt(0)" ::: "memory");

#define STAGE_NEXT(COND)                                                       \
  if (COND) {                                                                  \
    _Pragma("unroll") for (int j_ = 0; j_ < 8; j_++) {                         \
      stage16(kst + koff[j_], kB + sdst[j_]);                                  \
      stage16(vst + voff[j_], vN + sdst[j_]);                                  \
    }                                                                          \
    kst += 4096; vst += 64;                                                    \
  }

#define QK(S0, S1)                                                             \
  {                                                                            \
    s16x8 kf0_[4], kf1_[4];                                                    \
    _Pragma("unroll") for (int s_ = 0; s_ < 4; s_++) {                         \
      kf0_[s_] = *(const s16x8*)(kA + rd0[s_]);                                \
      kf1_[s_] = *(const s16x8*)(kA + rd0[s_] + 2048);                         \
    }                                                                          \
    __builtin_amdgcn_s_setprio(1);                                             \
    S0 = __builtin_amdgcn_mfma_f32_32x32x16_bf16(kf0_[0], qf[0], Z, 0, 0, 0);  \
    S1 = __builtin_amdgcn_mfma_f32_32x32x16_bf16(kf1_[0], qf[0], Z, 0, 0, 0);  \
    _Pragma("unroll") for (int s_ = 1; s_ < 4; s_++) {                         \
      S0 = __builtin_amdgcn_mfma_f32_32x32x16_bf16(kf0_[s_], qf[s_], S0, 0, 0, 0); \
      S1 = __builtin_amdgcn_mfma_f32_32x32x16_bf16(kf1_[s_], qf[s_], S1, 0, 0, 0); \
    }                                                                          \
    __builtin_amdgcn_s_setprio(0);                                             \
  }

#define SMPV_BODY(S0, S1)                                                      \
  {                                                                            \
    float rsum_ = 0.f;                                                         \
    _Pragma("unroll") for (int r2_ = 0; r2_ < 16; r2_++) {                     \
      float p_ = __builtin_amdgcn_exp2f(S0[r2_]);                              \
      S0[r2_] = p_; rsum_ += p_;                                               \
    }                                                                          \
    _Pragma("unroll") for (int r2_ = 0; r2_ < 16; r2_++) {                     \
      float p_ = __builtin_amdgcn_exp2f(S1[r2_]);                              \
      S1[r2_] = p_; rsum_ += p_;                                               \
    }                                                                          \
    l += rsum_;                                                                \
    unsigned pk0_[8], pk1_[8];                                                 \
    _Pragma("unroll") for (int j_ = 0; j_ < 8; j_++) {                         \
      unsigned u_;                                                             \
      float a0_ = S0[2 * j_], a1_ = S0[2 * j_ + 1];                            \
      asm("v_cvt_pk_bf16_f32 %0, %1, %2" : "=v"(u_) : "v"(a0_), "v"(a1_));     \
      pk0_[j_] = u_;                                                           \
      float b0_ = S1[2 * j_], b1_ = S1[2 * j_ + 1];                            \
      asm("v_cvt_pk_bf16_f32 %0, %1, %2" : "=v"(u_) : "v"(b0_), "v"(b1_));     \
      pk1_[j_] = u_;                                                           \
    }                                                                          \
    _Pragma("unroll") for (int s_ = 0; s_ < 4; s_++) {                         \
      const unsigned* pk_ = (s_ < 2) ? pk0_ : pk1_;                            \
      const int b_ = 4 * (s_ & 1);                                             \
      auto rA_ = __builtin_amdgcn_permlane32_swap(pk_[b_ + 0], pk_[b_ + 2], false, false); \
      auto rB_ = __builtin_amdgcn_permlane32_swap(pk_[b_ + 1], pk_[b_ + 3], false, false); \
      union { unsigned u[4]; s16x8 v; } fr_;                                   \
      fr_.u[0] = rA_[0]; fr_.u[1] = rB_[0]; fr_.u[2] = rA_[1]; fr_.u[3] = rB_[1]; \
      s16x8 vf0_ = *(const s16x8*)(vP + rd0[s_]);                              \
      s16x8 vf1_ = *(const s16x8*)(vP + rd0[s_] + 2048);                       \
      __builtin_amdgcn_s_setprio(1);                                           \
      accA = __builtin_amdgcn_mfma_f32_32x32x16_bf16(vf0_, fr_.v, accA, 0, 0, 0); \
      accB = __builtin_amdgcn_mfma_f32_32x32x16_bf16(vf1_, fr_.v, accB, 0, 0, 0); \
      __builtin_amdgcn_s_setprio(0);                                           \
    }                                                                          \
  }

#define SMPV_MASK(S0, S1)                                                      \
  {                                                                            \
    const int k0_ = (nt - 1) * 64;                                             \
    _Pragma("unroll") for (int r2_ = 0; r2_ < 16; r2_++) {                     \
      int kvr_ = k0_ + (r2_ & 3) + 8 * (r2_ >> 2) + 4 * hi;                    \
      if (kvr_ > qrow) S0[r2_] = -__builtin_inff();                            \
      if (kvr_ + 32 > qrow) S1[r2_] = -__builtin_inff();                       \
    }                                                                          \
    SMPV_BODY(S0, S1)                                                          \
  }

#define ROT()                                                                  \
  {                                                                            \
    short* t_ = kA; kA = kB; kB = t_;                                          \
    t_ = vP; vP = vC; vC = vN; vN = t_;                                        \
  }

  f32x16 sA0, sA1, sB0, sB1;
  SYNC
  STAGE_NEXT(nt > 1)
  QK(sA0, sA1)
  ROT()
  int t = 1;
  for (; t + 1 < nt; t += 2) {
    SYNC
    STAGE_NEXT(t + 1 < nt)
    QK(sB0, sB1)
    SMPV_BODY(sA0, sA1)
    ROT()
    SYNC
    STAGE_NEXT(t + 2 < nt)
    QK(sA0, sA1)
    SMPV_BODY(sB0, sB1)
    ROT()
  }
  if (t < nt) {
    SYNC
    QK(sB0, sB1)
    SMPV_BODY(sA0, sA1)
    ROT()
    SMPV_MASK(sB0, sB1)
  } else {
    SMPV_MASK(sA0, sA1)
  }
#undef SYNC
#undef STAGE_NEXT
#undef QK
#undef SMPV_BODY
#undef SMPV_MASK
#undef ROT

  const int b_ = bh >> 4, h_ = bh & 15;
  const float lt = l + xhalf_f(l);
  const float invl = 1.f / lt;
  const size_t base2 = ((size_t)b_ * 2048 + qrow) * 1024 + h_ * 64;
#pragma unroll
  for (int gg = 0; gg < 4; gg++) {
    s16x4 o0, o1;
#pragma unroll
    for (int e = 0; e < 4; e++) {
      o0[e] = f2bf(accA[4 * gg + e] * invl);
      o1[e] = f2bf(accB[4 * gg + e] * invl);
    }
    *(s16x4*)(Y + base2 + 8 * gg + 4 * hi) = o0;
    *(s16x4*)(Y + base2 + 32 + 8 * gg + 4 * hi) = o1;
  }
}

extern "C" void kernel_launch(void* const* d_in, const int* in_sizes, int n_in,
                              void* d_out, int out_size, void* d_ws, size_t ws_size,
                              hipStream_t stream) {
  const float* x = (const float*)d_in[0];
  const float* Wq = (const float*)d_in[1];
  const float* bq = (const float*)d_in[2];
  const float* Wk = (const float*)d_in[3];
  const float* bk = (const float*)d_in[4];
  const float* Wv = (const float*)d_in[5];
  const float* bv = (const float*)d_in[6];
  const float* Wp = (const float*)d_in[7];
  const float* bp = (const float*)d_in[8];
  float* out = (float*)d_out;
  char* ws = (char*)d_ws;

  short* xb    = (short*)(ws + 0);         // 8 MB, reused as Y after QKV GEMM
  short* WqkvT = (short*)(ws + 8388608);   // 6 MB [3072][1024]
  short* WpT   = (short*)(ws + 14680064);  // 2 MB
  short* Qb    = (short*)(ws + 16777216);  // 8 MB [B,H,T,D] (pre-scaled 0.125*L2E)
  short* Kb    = (short*)(ws + 25165824);  // 8 MB [B,H,T,D]
  short* Vtb   = (short*)(ws + 33554432);  // 8 MB [B,H,D,T]
  short* Yb    = xb;

  prepass<<<dim3(16, 16, 12), 256, 0, stream>>>(Wq, Wk, Wv, Wp, WqkvT, x, xb);
  gemm_qkv8<<<256, 512, 0, stream>>>(xb, WqkvT, bq, bk, bv, Qb, Kb, Vtb);
  attn_v11<<<dim3(32, 32), 128, 0, stream>>>(Qb, Kb, Vtb, Yb);
  gemm_bt<1, 64><<<dim3(8, 64), 128, 0, stream>>>(Yb, WpT, 1024, 1024, bp, out);
}

// Round 22
// 101.021 us; speedup vs baseline: 1.1038x; 1.1038x over previous
//
#include <hip/hip_runtime.h>
#include <cstdint>

typedef __attribute__((ext_vector_type(4))) short s16x4;
typedef __attribute__((ext_vector_type(8))) short s16x8;
typedef __attribute__((ext_vector_type(4))) float f32x4;
typedef __attribute__((ext_vector_type(16))) float f32x16;

#define L2E 1.44269504088896340736f

__device__ __forceinline__ short f2bf(float f) {
  union { float f; unsigned u; } v; v.f = f;
  unsigned r = (v.u + 0x7fffu + ((v.u >> 16) & 1u)) >> 16;
  return (short)r;
}

// cross-half (lane ^ 32) exchange via permlane32_swap — pure VALU, no LDS.
__device__ __forceinline__ float xhalf_f(float x) {
  union { float f; unsigned u; } a; a.f = x;
  auto r = __builtin_amdgcn_permlane32_swap(a.u, a.u, false, false);
  union { unsigned u; float f; } b;
  b.u = (threadIdx.x & 32) ? r[0] : r[1];
  return b.f;
}

typedef const __attribute__((address_space(1))) unsigned int* gas_p;
typedef __attribute__((address_space(3))) unsigned int* las_p;
__device__ __forceinline__ void stage16(const void* g, void* l) {
  __builtin_amdgcn_global_load_lds((gas_p)(uintptr_t)g,
                                   (las_p)(unsigned int)(uintptr_t)l, 16, 0, 0);
}

// ---- fused pre-pass: z<4 -> transpose W_z (1024x1024 fp32 -> bf16 [N][K]);
//      z>=4 -> cvt slab of x (fp32 -> bf16). One dispatch. ----
__global__ __launch_bounds__(256) void prepass(const float* __restrict__ W0,
                                               const float* __restrict__ W1,
                                               const float* __restrict__ W2,
                                               const float* __restrict__ W3,
                                               short* __restrict__ wdst,
                                               const float* __restrict__ x,
                                               short* __restrict__ xb) {
  const int z = blockIdx.z;
  const int t = threadIdx.x;
  if (z >= 4) {
    int i = ((z - 4) * 256 + blockIdx.y * 16 + blockIdx.x) * 256 + t;
    const f32x4* p = (const f32x4*)x + (size_t)i * 2;
    f32x4 a = p[0], b = p[1];
    s16x8 o;
    o[0] = f2bf(a[0]); o[1] = f2bf(a[1]); o[2] = f2bf(a[2]); o[3] = f2bf(a[3]);
    o[4] = f2bf(b[0]); o[5] = f2bf(b[1]); o[6] = f2bf(b[2]); o[7] = f2bf(b[3]);
    *((s16x8*)xb + i) = o;
    return;
  }
  __shared__ float tile[64][65];
  const float* in = (z == 0) ? W0 : (z == 1) ? W1 : (z == 2) ? W2 : W3;
  short* out = wdst + (size_t)z * 1048576;
  const int bi = blockIdx.y, bj = blockIdx.x;
  const int c = t & 63, r0 = t >> 6;
#pragma unroll
  for (int i = 0; i < 16; i++) {
    int r = r0 + i * 4;
    tile[r][c] = in[(size_t)(bi * 64 + r) * 1024 + bj * 64 + c];
  }
  __syncthreads();
#pragma unroll
  for (int i = 0; i < 16; i++) {
    int r = r0 + i * 4;
    out[(size_t)(bj * 64 + r) * 1024 + bi * 64 + c] = f2bf(tile[c][r]);
  }
}

// ======== QKV GEMM: 8-phase 256x192 schedule (full CU coverage) ========
// C[4096,3072] = A[4096,1024] * B[3072,1024]^T, K=1024 (16 K-tiles of 64).
// Grid 256 blocks (16 M x 16 N) = 1/CU on ALL 256 CUs. 512 thr = 8 waves
// (2M x 4N), wave tile 128x48, 48 MFMA/wave/K-tile in 4 phases of 12.
// LDS 112 KB = 2 parity buffers x {A[256][64], B[192][64]} bf16, chunk-XOR
// swizzled (ch ^= row&7) via pre-swizzled source + linear dest. Staging/tile
// t: p0 A-hi(t+1); p1 B-lo(t+2); p2 B-hi(t+2); p3 A-lo(t+2) then vmcnt(5).
__global__ __launch_bounds__(512) void gemm_qkv8(
    const short* __restrict__ A, const short* __restrict__ B,
    const float* __restrict__ b0, const float* __restrict__ b1,
    const float* __restrict__ b2, short* __restrict__ o0,
    short* __restrict__ o1, short* __restrict__ o2) {
  constexpr int K = 1024, NKT = 16;
  constexpr int BUFS = 28672;  // shorts per parity buffer (A 16384 + B 12288)
  __shared__ short L[2 * BUFS];  // 112 KB
  const int tid = threadIdx.x;
  const int lane = tid & 63, wave = tid >> 6;
  const int wr = wave >> 2, wc = wave & 3;
  const int l15 = lane & 15, l4 = lane >> 4;
  const int id = blockIdx.x;
  const int wgid = (id & 7) * 32 + (id >> 3);
  const int m0 = (wgid & 15) * 256;
  const int n0 = (wgid >> 4) * 192;
  const short* Asrc = A + (size_t)m0 * K;
  const short* Bsrc = B + (size_t)n0 * K;

  f32x4 acc[8][3];
#pragma unroll
  for (int i = 0; i < 8; i++)
#pragma unroll
    for (int j = 0; j < 3; j++) acc[i][j] = (f32x4){0.f, 0.f, 0.f, 0.f};

  int sALo[2], gALo[2], sBLo[2], gBLo[2];
#pragma unroll
  for (int j = 0; j < 2; j++) {
    const int flat = j * 512 + tid;
    const int r = flat >> 3, ch = flat & 7;
    const int sw8 = ((ch ^ (r & 7)) << 3);
    sALo[j] = (r >> 6) * 8192 + (r & 63) * 64 + (ch << 3);
    gALo[j] = ((r >> 6) * 128 + (r & 63)) * K + sw8;
    sBLo[j] = 16384 + (flat << 3);
    gBLo[j] = r * K + sw8;
  }
  const int rBH = 128 + (tid >> 3), chBH = tid & 7;
  const int sBHi = 16384 + rBH * 64 + (chBH << 3);
  const int gBHi = rBH * K + ((chBH ^ (rBH & 7)) << 3);

  int aoff[2], boff[2];
#pragma unroll
  for (int kf = 0; kf < 2; kf++) {
    const int x = (((kf << 2) + l4) ^ (l15 & 7)) << 3;
    aoff[kf] = wr * 8192 + l15 * 64 + x;
    boff[kf] = 16384 + (wc * 48 + l15) * 64 + x;
  }

#define ST_ALO(BB, T)                                                          \
  { _Pragma("unroll") for (int j_ = 0; j_ < 2; j_++)                           \
        stage16(Asrc + gALo[j_] + (T)*64, L + (BB) + sALo[j_]); }
#define ST_AHI(BB, T)                                                          \
  { _Pragma("unroll") for (int j_ = 0; j_ < 2; j_++)                           \
        stage16(Asrc + gALo[j_] + 64 * K + (T)*64, L + (BB) + sALo[j_] + 4096); }
#define ST_BLO(BB, T)                                                          \
  { _Pragma("unroll") for (int j_ = 0; j_ < 2; j_++)                           \
        stage16(Bsrc + gBLo[j_] + (T)*64, L + (BB) + sBLo[j_]); }
#define ST_BHI(BB, T)                                                          \
  stage16(Bsrc + gBHi + (T)*64, L + (BB) + sBHi);

#define RD_A(MI0)                                                              \
  { _Pragma("unroll") for (int q_ = 0; q_ < 2; q_++)                           \
        _Pragma("unroll") for (int kf_ = 0; kf_ < 2; kf_++)                    \
            af[q_][kf_] = *(const s16x8*)(bc + aoff[kf_] + ((MI0) + q_) * 1024); }

#define BAR_MFMA(MI0)                                                          \
  __builtin_amdgcn_s_barrier();                                                \
  asm volatile("s_waitcnt lgkmcnt(0)" ::: "memory");                           \
  __builtin_amdgcn_sched_barrier(0);                                           \
  __builtin_amdgcn_s_setprio(1);                                               \
  _Pragma("unroll") for (int q_ = 0; q_ < 2; q_++)                             \
      _Pragma("unroll") for (int ni_ = 0; ni_ < 3; ni_++)                      \
          _Pragma("unroll") for (int kf_ = 0; kf_ < 2; kf_++)                  \
              acc[(MI0) + q_][ni_] = __builtin_amdgcn_mfma_f32_16x16x32_bf16(  \
                  af[q_][kf_], bf[ni_][kf_], acc[(MI0) + q_][ni_], 0, 0, 0);   \
  __builtin_amdgcn_s_setprio(0);                                               \
  __builtin_amdgcn_s_barrier();

  ST_ALO(0, 0) ST_AHI(0, 0) ST_BLO(0, 0) ST_BHI(0, 0)
  ST_BLO(BUFS, 1) ST_BHI(BUFS, 1) ST_ALO(BUFS, 1)
  asm volatile("s_waitcnt vmcnt(5)" ::: "memory");
  __builtin_amdgcn_s_barrier();

  int bufc = 0;
  for (int t = 0; t < NKT; ++t) {
    const int bufn = bufc ^ BUFS;
    const short* bc = L + bufc;
    s16x8 bf[3][2], af[2][2];
#pragma unroll
    for (int ni_ = 0; ni_ < 3; ni_++)
#pragma unroll
      for (int kf_ = 0; kf_ < 2; kf_++)
        bf[ni_][kf_] = *(const s16x8*)(bc + boff[kf_] + ni_ * 1024);
    RD_A(0)
    if (t + 1 < NKT) ST_AHI(bufn, t + 1)
    BAR_MFMA(0)
    RD_A(2)
    if (t + 2 < NKT) ST_BLO(bufc, t + 2)
    BAR_MFMA(2)
    RD_A(4)
    if (t + 2 < NKT) ST_BHI(bufc, t + 2)
    BAR_MFMA(4)
    RD_A(6)
    if (t + 2 < NKT) {
      ST_ALO(bufc, t + 2)
      asm volatile("s_waitcnt vmcnt(5)" ::: "memory");
    } else {
      asm volatile("s_waitcnt vmcnt(0)" ::: "memory");
    }
    BAR_MFMA(6)
    bufc = bufn;
  }
#undef ST_ALO
#undef ST_AHI
#undef ST_BLO
#undef ST_BHI
#undef RD_A
#undef BAR_MFMA

#pragma unroll
  for (int ni = 0; ni < 3; ni++) {
    const int col = n0 + wc * 48 + ni * 16 + l15;
    const float* bp; short* dst; int c1; int isV = 0; float scl = 1.0f;
    if (col < 1024) { bp = b0; dst = o0; c1 = col; scl = 0.125f * L2E; }
    else if (col < 2048) { bp = b1; dst = o1; c1 = col - 1024; }
    else { bp = b2; dst = o2; c1 = col - 2048; isV = 1; }
    const float bias = bp[c1];
    const int h = c1 >> 6, d = c1 & 63;
    if (isV) {
#pragma unroll
      for (int mi = 0; mi < 8; mi++) {
        int t0 = m0 + wr * 128 + mi * 16 + l4 * 4;
        int bb = t0 >> 11, tt = t0 & 2047;
        s16x4 ov;
#pragma unroll
        for (int rr = 0; rr < 4; rr++) ov[rr] = f2bf(acc[mi][ni][rr] + bias);
        *(s16x4*)(dst + (size_t)((bb * 16 + h) * 64 + d) * 2048 + tt) = ov;
      }
    } else {
#pragma unroll
      for (int mi = 0; mi < 8; mi++)
#pragma unroll
        for (int rr = 0; rr < 4; rr++) {
          int row = m0 + wr * 128 + mi * 16 + l4 * 4 + rr;
          int bb = row >> 11, tt = row & 2047;
          float v = (acc[mi][ni][rr] + bias) * scl;
          dst[(size_t)((bb * 16 + h) * 2048 + tt) * 64 + d] = f2bf(v);
        }
    }
  }
}

// ---------------- proj GEMM: 2-phase pipeline ----------------
template <int EPI, int BM>
__global__ __launch_bounds__(BM * 2) void gemm_bt(
    const short* __restrict__ A, const short* __restrict__ B, int N, int K,
    const float* __restrict__ b0, float* __restrict__ ofp) {
  constexpr int T = BM * 2;
  constexpr int AR = 2;
  constexpr int BR = 512 / T;
  constexpr int BUFB = (BM + 128) * 32;
  __shared__ short L[2 * BUFB];
  const int tid = threadIdx.x;
  const int lane = tid & 63;
  const int wave = tid >> 6;
  const int wr = wave >> 1, wc = wave & 1;
  const int l15 = lane & 15, l4 = lane >> 4;
  const int id = blockIdx.x + gridDim.x * blockIdx.y;
  const int cpx = gridDim.x >> 3;
  const int xcd = id & 7, sub = id >> 3;
  const int m0 = (sub / cpx) * BM;
  const int n0 = (xcd * cpx + sub % cpx) * 128;
  f32x4 acc[4][4];
#pragma unroll
  for (int i = 0; i < 4; i++)
#pragma unroll
    for (int j = 0; j < 4; j++) acc[i][j] = (f32x4){0.f, 0.f, 0.f, 0.f};

  const int lq = tid & 3, lr = tid >> 2;
  int soffA[AR], goffA[AR];
#pragma unroll
  for (int i = 0; i < AR; i++) {
    const int r = i * (T / 4) + lr;
    soffA[i] = r * 32 + lq * 8;
    goffA[i] = r * K + lq * 8;
  }
  int soffB[BR], goffB[BR];
#pragma unroll
  for (int j = 0; j < BR; j++) {
    const int r = j * (T / 4) + lr;
    soffB[j] = BM * 32 + r * 32 + lq * 8;
    goffB[j] = r * K + lq * 8;
  }

  const short* Asrc = A + (size_t)m0 * K;
  const short* Bsrc = B + (size_t)n0 * K;
  short* bufC = L;
  short* bufN = L + BUFB;

#define GSTAGE(BUF)                                                            \
  {                                                                            \
    _Pragma("unroll") for (int i_ = 0; i_ < AR; i_++)                          \
        stage16(Asrc + goffA[i_], (BUF) + soffA[i_]);                          \
    _Pragma("unroll") for (int j_ = 0; j_ < BR; j_++)                          \
        stage16(Bsrc + goffB[j_], (BUF) + soffB[j_]);                          \
    Asrc += 32; Bsrc += 32;                                                    \
  }

  GSTAGE(bufC)
  const int NK = K >> 5;
  for (int kt = 0; kt < NK; kt++) {
    __syncthreads();
    if (kt + 1 < NK) GSTAGE(bufN)
    s16x8 af[4], bfr[4];
#pragma unroll
    for (int i = 0; i < 4; i++) {
      af[i] = *(const s16x8*)(bufC + (wr * 64 + i * 16 + l15) * 32 + l4 * 8);
      bfr[i] = *(const s16x8*)(bufC + BM * 32 + (wc * 64 + i * 16 + l15) * 32 + l4 * 8);
    }
#pragma unroll
    for (int mi = 0; mi < 4; mi++)
#pragma unroll
      for (int ni = 0; ni < 4; ni++)
        acc[mi][ni] = __builtin_amdgcn_mfma_f32_16x16x32_bf16(af[mi], bfr[ni],
                                                              acc[mi][ni], 0, 0, 0);
    short* t_ = bufC; bufC = bufN; bufN = t_;
  }
#undef GSTAGE

#pragma unroll
  for (int ni = 0; ni < 4; ni++) {
    const int col = n0 + wc * 64 + ni * 16 + l15;
    const float bias = b0[col];
#pragma unroll
    for (int mi = 0; mi < 4; mi++)
#pragma unroll
      for (int r = 0; r < 4; r++) {
        int row = m0 + wr * 64 + mi * 16 + l4 * 4 + r;
        ofp[(size_t)row * N + col] = acc[mi][ni][r] + bias;
      }
  }
}

// ---- causal flash attention v8: CU-balanced qt assignment ----
__global__ __launch_bounds__(128) void attn_v8(const short* __restrict__ Q,
                                               const short* __restrict__ K,
                                               const short* __restrict__ Vt,
                                               short* __restrict__ Y) {
  __shared__ short Ks[2][64 * 64];
  __shared__ short Vs[3][64 * 64];
  const int bh = blockIdx.x;
  const int y = blockIdx.y;
  const int g = y >> 3, r_ = y & 7;
  const int qbase = (g << 3) | ((g & 1) ? (7 - r_) : r_);
  const int qt = (qbase + ((bh & 3) << 3)) & 31;
  const int tid = threadIdx.x, lane = tid & 63, wave = tid >> 6;
  const int q31 = lane & 31, hi = lane >> 5;
  const short* Qp = Q + (size_t)bh * 2048 * 64;
  const short* Kp = K + (size_t)bh * 2048 * 64;
  const short* Vp = Vt + (size_t)bh * 64 * 2048;
  const int qrow = qt * 64 + wave * 32 + q31;
  const int nt = qt + 1;
  const int cx = q31 & 7;

  s16x8 qf[4];
#pragma unroll
  for (int s = 0; s < 4; s++)
    qf[s] = *(const s16x8*)(Qp + (size_t)qrow * 64 + s * 16 + hi * 8);

  f32x16 accA, accB, Z;
#pragma unroll
  for (int i = 0; i < 16; i++) { accA[i] = 0.f; accB[i] = 0.f; Z[i] = 0.f; }
  float l = 0.f;

  const int srow = tid >> 3, sch = tid & 7;
  int sdst[4], koff[4], voff[4];
#pragma unroll
  for (int i = 0; i < 4; i++) {
    const int r = srow + i * 16;
    const int sc = sch ^ (r & 7);
    sdst[i] = r * 64 + sch * 8;
    koff[i] = r * 64 + sc * 8;
    voff[i] = r * 2048 + sc * 8;
  }
  const short* kst = Kp;
  const short* vst = Vp;
  int rd0[4];
#pragma unroll
  for (int s = 0; s < 4; s++) rd0[s] = q31 * 64 + (((2 * s + hi) ^ cx) << 3);

  short* kA = &Ks[0][0]; short* kB = &Ks[1][0];
  short* vP = &Vs[2][0]; short* vC = &Vs[0][0]; short* vN = &Vs[1][0];

#pragma unroll
  for (int i = 0; i < 4; i++) {
    stage16(kst + koff[i], kA + sdst[i]);
    stage16(vst + voff[i], vC + sdst[i]);
  }
  kst += 4096; vst += 64;

#define STAGE_NEXT(COND)                                                       \
  if (COND) {                                                                  \
    _Pragma("unroll") for (int i_ = 0; i_ < 4; i_++) {                         \
      stage16(kst + koff[i_], kB + sdst[i_]);                                  \
      stage16(vst + voff[i_], vN + sdst[i_]);                                  \
    }                                                                          \
    kst += 4096; vst += 64;                                                    \
  }

#define QK(S0, S1)                                                             \
  {                                                                            \
    s16x8 kf0_[4], kf1_[4];                                                    \
    _Pragma("unroll") for (int s_ = 0; s_ < 4; s_++) {                         \
      kf0_[s_] = *(const s16x8*)(kA + rd0[s_]);                                \
      kf1_[s_] = *(const s16x8*)(kA + rd0[s_] + 2048);                         \
    }                                                                          \
    __builtin_amdgcn_s_setprio(1);                                             \
    S0 = __builtin_amdgcn_mfma_f32_32x32x16_bf16(kf0_[0], qf[0], Z, 0, 0, 0);  \
    S1 = __builtin_amdgcn_mfma_f32_32x32x16_bf16(kf1_[0], qf[0], Z, 0, 0, 0);  \
    _Pragma("unroll") for (int s_ = 1; s_ < 4; s_++) {                         \
      S0 = __builtin_amdgcn_mfma_f32_32x32x16_bf16(kf0_[s_], qf[s_], S0, 0, 0, 0); \
      S1 = __builtin_amdgcn_mfma_f32_32x32x16_bf16(kf1_[s_], qf[s_], S1, 0, 0, 0); \
    }                                                                          \
    __builtin_amdgcn_s_setprio(0);                                             \
  }

#define SMPV_BODY(S0, S1)                                                      \
  {                                                                            \
    float rsum_ = 0.f;                                                         \
    _Pragma("unroll") for (int r2_ = 0; r2_ < 16; r2_++) {                     \
      float p_ = __builtin_amdgcn_exp2f(S0[r2_]);                              \
      S0[r2_] = p_; rsum_ += p_;                                               \
    }                                                                          \
    _Pragma("unroll") for (int r2_ = 0; r2_ < 16; r2_++) {                     \
      float p_ = __builtin_amdgcn_exp2f(S1[r2_]);                              \
      S1[r2_] = p_; rsum_ += p_;                                               \
    }                                                                          \
    l += rsum_;                                                                \
    unsigned pk0_[8], pk1_[8];                                                 \
    _Pragma("unroll") for (int j_ = 0; j_ < 8; j_++) {                         \
      unsigned u_;                                                             \
      float a0_ = S0[2 * j_], a1_ = S0[2 * j_ + 1];                            \
      asm("v_cvt_pk_bf16_f32 %0, %1, %2" : "=v"(u_) : "v"(a0_), "v"(a1_));     \
      pk0_[j_] = u_;                                                           \
      float b0_ = S1[2 * j_], b1_ = S1[2 * j_ + 1];                            \
      asm("v_cvt_pk_bf16_f32 %0, %1, %2" : "=v"(u_) : "v"(b0_), "v"(b1_));     \
      pk1_[j_] = u_;                                                           \
    }                                                                          \
    _Pragma("unroll") for (int s_ = 0; s_ < 4; s_++) {                         \
      const unsigned* pk_ = (s_ < 2) ? pk0_ : pk1_;                            \
      const int b_ = 4 * (s_ & 1);                                             \
      auto rA_ = __builtin_amdgcn_permlane32_swap(pk_[b_ + 0], pk_[b_ + 2], false, false); \
      auto rB_ = __builtin_amdgcn_permlane32_swap(pk_[b_ + 1], pk_[b_ + 3], false, false); \
      union { unsigned u[4]; s16x8 v; } fr_;                                   \
      fr_.u[0] = rA_[0]; fr_.u[1] = rB_[0]; fr_.u[2] = rA_[1]; fr_.u[3] = rB_[1]; \
      s16x8 vf0_ = *(const s16x8*)(vP + rd0[s_]);                              \
      s16x8 vf1_ = *(const s16x8*)(vP + rd0[s_] + 2048);                       \
      __builtin_amdgcn_s_setprio(1);                                           \
      accA = __builtin_amdgcn_mfma_f32_32x32x16_bf16(vf0_, fr_.v, accA, 0, 0, 0); \
      accB = __builtin_amdgcn_mfma_f32_32x32x16_bf16(vf1_, fr_.v, accB, 0, 0, 0); \
      __builtin_amdgcn_s_setprio(0);                                           \
    }                                                                          \
  }

#define SMPV_MASK(S0, S1)                                                      \
  {                                                                            \
    const int k0_ = (nt - 1) * 64;                                             \
    _Pragma("unroll") for (int r2_ = 0; r2_ < 16; r2_++) {                     \
      int kvr_ = k0_ + (r2_ & 3) + 8 * (r2_ >> 2) + 4 * hi;                    \
      if (kvr_ > qrow) S0[r2_] = -__builtin_inff();                            \
      if (kvr_ + 32 > qrow) S1[r2_] = -__builtin_inff();                       \
    }                                                                          \
    SMPV_BODY(S0, S1)                                                          \
  }

#define ROT()                                                                  \
  {                                                                            \
    short* t_ = kA; kA = kB; kB = t_;                                          \
    t_ = vP; vP = vC; vC = vN; vN = t_;                                        \
  }

  f32x16 sA0, sA1, sB0, sB1;
  __syncthreads();
  STAGE_NEXT(nt > 1)
  QK(sA0, sA1)
  ROT()
  int t = 1;
  for (; t + 1 < nt; t += 2) {
    __syncthreads();
    STAGE_NEXT(t + 1 < nt)
    QK(sB0, sB1)
    SMPV_BODY(sA0, sA1)
    ROT()
    __syncthreads();
    STAGE_NEXT(t + 2 < nt)
    QK(sA0, sA1)
    SMPV_BODY(sB0, sB1)
    ROT()
  }
  if (t < nt) {
    __syncthreads();
    QK(sB0, sB1)
    SMPV_BODY(sA0, sA1)
    ROT()
    SMPV_MASK(sB0, sB1)
  } else {
    SMPV_MASK(sA0, sA1)
  }
#undef STAGE_NEXT
#undef QK
#undef SMPV_BODY
#undef SMPV_MASK
#undef ROT

  const int b_ = bh >> 4, h_ = bh & 15;
  const float lt = l + xhalf_f(l);
  const float invl = 1.f / lt;
  const size_t base = ((size_t)b_ * 2048 + qrow) * 1024 + h_ * 64;
#pragma unroll
  for (int gg = 0; gg < 4; gg++) {
    s16x4 o0, o1;
#pragma unroll
    for (int e = 0; e < 4; e++) {
      o0[e] = f2bf(accA[4 * gg + e] * invl);
      o1[e] = f2bf(accB[4 * gg + e] * invl);
    }
    *(s16x4*)(Y + base + 8 * gg + 4 * hi) = o0;
    *(s16x4*)(Y + base + 32 + 8 * gg + 4 * hi) = o1;
  }
}

extern "C" void kernel_launch(void* const* d_in, const int* in_sizes, int n_in,
                              void* d_out, int out_size, void* d_ws, size_t ws_size,
                              hipStream_t stream) {
  const float* x = (const float*)d_in[0];
  const float* Wq = (const float*)d_in[1];
  const float* bq = (const float*)d_in[2];
  const float* Wk = (const float*)d_in[3];
  const float* bk = (const float*)d_in[4];
  const float* Wv = (const float*)d_in[5];
  const float* bv = (const float*)d_in[6];
  const float* Wp = (const float*)d_in[7];
  const float* bp = (const float*)d_in[8];
  float* out = (float*)d_out;
  char* ws = (char*)d_ws;

  short* xb    = (short*)(ws + 0);         // 8 MB, reused as Y after QKV GEMM
  short* WqkvT = (short*)(ws + 8388608);   // 6 MB [3072][1024]
  short* WpT   = (short*)(ws + 14680064);  // 2 MB
  short* Qb    = (short*)(ws + 16777216);  // 8 MB [B,H,T,D] (pre-scaled 0.125*L2E)
  short* Kb    = (short*)(ws + 25165824);  // 8 MB [B,H,T,D]
  short* Vtb   = (short*)(ws + 33554432);  // 8 MB [B,H,D,T]
  short* Yb    = xb;

  prepass<<<dim3(16, 16, 12), 256, 0, stream>>>(Wq, Wk, Wv, Wp, WqkvT, x, xb);
  gemm_qkv8<<<256, 512, 0, stream>>>(xb, WqkvT, bq, bk, bv, Qb, Kb, Vtb);
  attn_v8<<<dim3(32, 32), 128, 0, stream>>>(Qb, Kb, Vtb, Yb);
  gemm_bt<1, 64><<<dim3(8, 64), 128, 0, stream>>>(Yb, WpT, 1024, 1024, bp, out);
}